// Round 13
// baseline (1080.610 us; speedup 1.0000x reference)
//
#include <hip/hip_runtime.h>
#include <hip/hip_bf16.h>
#include <hip/hip_cooperative_groups.h>

namespace cg = cooperative_groups;

#define NUM_USERS 100000
#define NUM_ITEMS 50000
#define EMBED     64
#define S_NNZ     (NUM_USERS * 32)
#define R_NNZ     (NUM_USERS * 50)
#define BATCH     8192

// bucket sort parameters: 512 buckets x 196 rows, 1024 chunks x 3125 edges
#define NB    512
#define NCH   1024
#define CHUNK (S_NNZ / NCH)      // 3125
#define BROWS 196                // 196*512 = 100352 >= NUM_USERS

#define SEGCAP 160               // per-slot R segment capacity (P(deg>160) ~ 1e-30)

// ---------------- cooperative fused CSR build ----------------
// 6 former kernels as grid.sync-separated phases. 1024 blocks x 256 thr,
// LDS 3KB, low VGPR -> 4+ blocks/CU co-resident (cooperative launch safe).

__global__ __launch_bounds__(256) void k_build(const int* __restrict__ rows,
                                               const int* __restrict__ cols,
                                               const float* __restrict__ vals,
                                               int* __restrict__ cnt_t,
                                               int* __restrict__ head,
                                               unsigned* __restrict__ bitmap,
                                               int* __restrict__ cntR,
                                               const int* __restrict__ bu,
                                               int* __restrict__ nxt,
                                               int2* __restrict__ tmpE,
                                               const float* __restrict__ U,
                                               __hip_bfloat16* __restrict__ U16,
                                               int* __restrict__ rowptr,
                                               int2* __restrict__ colval,
                                               int* __restrict__ bsums) {
    cg::grid_group grid = cg::this_grid();
    __shared__ int sh[768];          // union across phases (max: p2 3x256, p1 hist 512)
    int t = threadIdx.x, b = blockIdx.x;
    int base = b * CHUNK;

    // ---- phase 1: init head/bitmap/cntR + per-chunk bucket histogram (block b = chunk b) ----
    for (int i = b * 256 + t; i < NUM_USERS; i += NCH * 256) head[i] = -1;
    for (int i = b * 256 + t; i < (NUM_USERS + 31) / 32; i += NCH * 256) bitmap[i] = 0;
    for (int i = b * 256 + t; i < BATCH; i += NCH * 256) cntR[i] = 0;
    for (int i = t; i < NB; i += 256) sh[i] = 0;
    __syncthreads();
    for (int i = t; i < CHUNK; i += 256) atomicAdd(&sh[rows[base + i] / BROWS], 1);
    __syncthreads();
    for (int i = t; i < NB; i += 256) cnt_t[i * NCH + b] = sh[i];
    grid.sync();

    // ---- phase 2a: block-local exclusive scan of 512 elems (2/thread) + chain map ----
    {
        int i = b * 256 + t;
        if (i < BATCH) {
            int u = bu[i];
            nxt[i] = atomicExch(&head[u], i);
            atomicOr(&bitmap[u >> 5], 1u << (u & 31));
        }
        int i0 = b * 512 + 2 * t;
        int x0 = cnt_t[i0], x1 = cnt_t[i0 + 1];
        int s2 = x0 + x1;
        sh[t] = s2;
        __syncthreads();
        for (int off = 1; off < 256; off <<= 1) {
            int y = (t >= off) ? sh[t - off] : 0;
            __syncthreads();
            sh[t] += y;
            __syncthreads();
        }
        int excl = sh[t] - s2;
        cnt_t[i0]     = excl;
        cnt_t[i0 + 1] = excl + x0;
        if (t == 255) bsums[b] = sh[255];
    }
    grid.sync();

    // ---- phase 2b: block 0 scans bsums[1024] (4/thread) ----
    if (b == 0) {
        int l0 = bsums[4 * t], l1 = bsums[4 * t + 1], l2 = bsums[4 * t + 2], l3 = bsums[4 * t + 3];
        int s4 = l0 + l1 + l2 + l3;
        sh[t] = s4;
        __syncthreads();
        for (int off = 1; off < 256; off <<= 1) {
            int y = (t >= off) ? sh[t - off] : 0;
            __syncthreads();
            sh[t] += y;
            __syncthreads();
        }
        int excl = sh[t] - s4;
        bsums[4 * t]     = excl;
        bsums[4 * t + 1] = excl + l0;
        bsums[4 * t + 2] = excl + l0 + l1;
        bsums[4 * t + 3] = excl + l0 + l1 + l2;
    }
    grid.sync();

    // ---- phase 2c: add block offsets ----
    {
        int off = bsums[b];
        int i0  = b * 512 + 2 * t;
        cnt_t[i0]     += off;
        cnt_t[i0 + 1] += off;
    }
    grid.sync();

    // ---- phase 3: scatter into per-(chunk,bucket) runs + U -> bf16 convert ----
    {
        for (int i = t; i < NB; i += 256) sh[i] = cnt_t[i * NCH + b];
        __syncthreads();
        for (int i = t; i < CHUNK; i += 256) {
            int e  = base + i;
            int r  = rows[e];
            int bk = r / BROWS;
            int pos = atomicAdd(&sh[bk], 1);
            tmpE[pos] = make_int2(((r - bk * BROWS) << 17) | cols[e], __float_as_int(vals[e]));
        }
        const int total = NUM_USERS * EMBED;
        for (int i = b * 256 + t; i < total; i += NCH * 256) U16[i] = __float2bfloat16(U[i]);
    }
    grid.sync();

    // ---- phase 4: per-bucket exact CSR (blocks 0..NB-1 active) ----
    if (b < NB) {
        int k   = b;
        int beg = cnt_t[k * NCH];
        int end = (k < NB - 1) ? cnt_t[(k + 1) * NCH] : S_NNZ;
        int* h2 = sh;
        int* s2 = sh + 256;
        int* cu = sh + 512;
        h2[t] = 0;
        __syncthreads();
        for (int j = beg + t; j < end; j += 256) atomicAdd(&h2[((unsigned)tmpE[j].x) >> 17], 1);
        __syncthreads();
        s2[t] = h2[t];
        __syncthreads();
        for (int off = 1; off < 256; off <<= 1) {
            int y = (t >= off) ? s2[t - off] : 0;
            __syncthreads();
            s2[t] += y;
            __syncthreads();
        }
        int excl = s2[t] - h2[t];
        int gr   = k * BROWS + t;
        if (t <= BROWS && gr <= NUM_USERS) rowptr[gr] = beg + excl;
        cu[t] = beg + excl;
        __syncthreads();
        for (int j = beg + t; j < end; j += 256) {
            int2 e  = tmpE[j];
            int pos = atomicAdd(&cu[((unsigned)e.x) >> 17], 1);
            colval[pos] = make_int2(e.x & 0x1FFFF, e.y);
        }
    }
}

// ---------------- SpMM: 2 rows per wave (adjacent CSR runs), 16 outstanding gathers ----
__global__ __launch_bounds__(256) void k_spmm16p(const int* __restrict__ rowptr,
                                                 const int2* __restrict__ colval,
                                                 const __hip_bfloat16* __restrict__ X,
                                                 float* __restrict__ Y, int n_pairs) {
    int w    = blockIdx.x * (blockDim.x >> 6) + (threadIdx.x >> 6);
    int lane = threadIdx.x & 63;
    if (w >= n_pairs) return;
    int r0   = 2 * w;
    int beg0 = rowptr[r0], mid = rowptr[r0 + 1], end1 = rowptr[r0 + 2];
    float acc0 = 0.0f, acc1 = 0.0f;
    int j0 = beg0, j1 = mid;
    int jend0 = beg0 + ((mid - beg0) & ~7);
    int jend1 = mid + ((end1 - mid) & ~7);
    while (j0 < jend0 && j1 < jend1) {
        int2 ca[8], cb[8];
#pragma unroll
        for (int u = 0; u < 8; ++u) ca[u] = colval[j0 + u];
#pragma unroll
        for (int u = 0; u < 8; ++u) cb[u] = colval[j1 + u];
        float xa[8], xb[8];
#pragma unroll
        for (int u = 0; u < 8; ++u) xa[u] = __bfloat162float(X[(size_t)ca[u].x * EMBED + lane]);
#pragma unroll
        for (int u = 0; u < 8; ++u) xb[u] = __bfloat162float(X[(size_t)cb[u].x * EMBED + lane]);
#pragma unroll
        for (int u = 0; u < 8; ++u) acc0 = fmaf(__int_as_float(ca[u].y), xa[u], acc0);
#pragma unroll
        for (int u = 0; u < 8; ++u) acc1 = fmaf(__int_as_float(cb[u].y), xb[u], acc1);
        j0 += 8; j1 += 8;
    }
    for (; j0 < jend0; j0 += 8) {
        int2 cv[8];
#pragma unroll
        for (int u = 0; u < 8; ++u) cv[u] = colval[j0 + u];
        float x[8];
#pragma unroll
        for (int u = 0; u < 8; ++u) x[u] = __bfloat162float(X[(size_t)cv[u].x * EMBED + lane]);
#pragma unroll
        for (int u = 0; u < 8; ++u) acc0 = fmaf(__int_as_float(cv[u].y), x[u], acc0);
    }
    for (; j1 < jend1; j1 += 8) {
        int2 cv[8];
#pragma unroll
        for (int u = 0; u < 8; ++u) cv[u] = colval[j1 + u];
        float x[8];
#pragma unroll
        for (int u = 0; u < 8; ++u) x[u] = __bfloat162float(X[(size_t)cv[u].x * EMBED + lane]);
#pragma unroll
        for (int u = 0; u < 8; ++u) acc1 = fmaf(__int_as_float(cv[u].y), x[u], acc1);
    }
    for (; j0 < mid; ++j0)
        acc0 = fmaf(__int_as_float(colval[j0].y), __bfloat162float(X[(size_t)colval[j0].x * EMBED + lane]), acc0);
    for (; j1 < end1; ++j1)
        acc1 = fmaf(__int_as_float(colval[j1].y), __bfloat162float(X[(size_t)colval[j1].x * EMBED + lane]), acc1);
    Y[(size_t)r0 * EMBED + lane]       = acc0;
    Y[(size_t)(r0 + 1) * EMBED + lane] = acc1;
}

__global__ __launch_bounds__(256) void k_spmm_batch16(const int* __restrict__ rowptr,
                                                      const int2* __restrict__ colval,
                                                      const __hip_bfloat16* __restrict__ X,
                                                      const int* __restrict__ bu,
                                                      float* __restrict__ Agg2, int n) {
    int w    = blockIdx.x * (blockDim.x >> 6) + (threadIdx.x >> 6);
    int lane = threadIdx.x & 63;
    if (w >= n) return;
    int r   = bu[w];
    int beg = rowptr[r], end = rowptr[r + 1];
    float acc = 0.0f;
    int j    = beg;
    int jend = beg + ((end - beg) & ~7);
    for (; j < jend; j += 8) {
        int2 cv[8];
#pragma unroll
        for (int u = 0; u < 8; ++u) cv[u] = colval[j + u];
        float x[8];
#pragma unroll
        for (int u = 0; u < 8; ++u) x[u] = __bfloat162float(X[(size_t)cv[u].x * EMBED + lane]);
#pragma unroll
        for (int u = 0; u < 8; ++u) acc = fmaf(__int_as_float(cv[u].y), x[u], acc);
    }
    for (; j < end; ++j)
        acc = fmaf(__int_as_float(colval[j].y), __bfloat162float(X[(size_t)colval[j].x * EMBED + lane]), acc);
    Agg2[(size_t)w * EMBED + lane] = acc;
}

// ---------------- dense layers (v2, 256-thread, proven) ----------------

__global__ __launch_bounds__(256) void k_layer(const float* __restrict__ Agg,
                                               const float* __restrict__ Uin,
                                               float* __restrict__ Uout,
                                               __hip_bfloat16* __restrict__ Uout16,
                                               const float* __restrict__ W,
                                               const float* __restrict__ b) {
    __shared__ __align__(16) float Wt[64 * 128];
    int t = threadIdx.x;
    for (int i = t; i < 128 * 64; i += 256) {
        int k = i >> 6, c = i & 63;
        Wt[c * 128 + ((((k >> 2) ^ (c & 7)) << 2) | (k & 3))] = W[i];
    }
    int rl = __builtin_amdgcn_readfirstlane(t >> 6);   // wave id 0..3 (wave-uniform)
    int c  = t & 63;
    int rbase = blockIdx.x * 16 + rl * 4;              // 6250*16 = 100000 exact, no guard
    __syncthreads();
    const float4* Wt4 = (const float4*)Wt;
    int  csw   = c & 7;
    int  cbase = c * 32;
    const float4* a0 = (const float4*)(Agg + (size_t)(rbase + 0) * EMBED);
    const float4* a1 = (const float4*)(Agg + (size_t)(rbase + 1) * EMBED);
    const float4* a2 = (const float4*)(Agg + (size_t)(rbase + 2) * EMBED);
    const float4* a3 = (const float4*)(Agg + (size_t)(rbase + 3) * EMBED);
    const float4* u0 = (const float4*)(Uin + (size_t)(rbase + 0) * EMBED);
    const float4* u1 = (const float4*)(Uin + (size_t)(rbase + 1) * EMBED);
    const float4* u2 = (const float4*)(Uin + (size_t)(rbase + 2) * EMBED);
    const float4* u3 = (const float4*)(Uin + (size_t)(rbase + 3) * EMBED);
    float bias = b[c];
    float acc0 = bias, acc1 = bias, acc2 = bias, acc3 = bias;
#pragma unroll 4
    for (int k4 = 0; k4 < 16; ++k4) {
        float4 w4 = Wt4[cbase + (k4 ^ csw)];
        float4 x0 = a0[k4], x1 = a1[k4], x2 = a2[k4], x3 = a3[k4];
        acc0 = fmaf(x0.x, w4.x, acc0); acc0 = fmaf(x0.y, w4.y, acc0); acc0 = fmaf(x0.z, w4.z, acc0); acc0 = fmaf(x0.w, w4.w, acc0);
        acc1 = fmaf(x1.x, w4.x, acc1); acc1 = fmaf(x1.y, w4.y, acc1); acc1 = fmaf(x1.z, w4.z, acc1); acc1 = fmaf(x1.w, w4.w, acc1);
        acc2 = fmaf(x2.x, w4.x, acc2); acc2 = fmaf(x2.y, w4.y, acc2); acc2 = fmaf(x2.z, w4.z, acc2); acc2 = fmaf(x2.w, w4.w, acc2);
        acc3 = fmaf(x3.x, w4.x, acc3); acc3 = fmaf(x3.y, w4.y, acc3); acc3 = fmaf(x3.z, w4.z, acc3); acc3 = fmaf(x3.w, w4.w, acc3);
    }
#pragma unroll 4
    for (int k4 = 16; k4 < 32; ++k4) {
        float4 w4 = Wt4[cbase + (k4 ^ csw)];
        float4 x0 = u0[k4 - 16], x1 = u1[k4 - 16], x2 = u2[k4 - 16], x3 = u3[k4 - 16];
        acc0 = fmaf(x0.x, w4.x, acc0); acc0 = fmaf(x0.y, w4.y, acc0); acc0 = fmaf(x0.z, w4.z, acc0); acc0 = fmaf(x0.w, w4.w, acc0);
        acc1 = fmaf(x1.x, w4.x, acc1); acc1 = fmaf(x1.y, w4.y, acc1); acc1 = fmaf(x1.z, w4.z, acc1); acc1 = fmaf(x1.w, w4.w, acc1);
        acc2 = fmaf(x2.x, w4.x, acc2); acc2 = fmaf(x2.y, w4.y, acc2); acc2 = fmaf(x2.z, w4.z, acc2); acc2 = fmaf(x2.w, w4.w, acc2);
        acc3 = fmaf(x3.x, w4.x, acc3); acc3 = fmaf(x3.y, w4.y, acc3); acc3 = fmaf(x3.z, w4.z, acc3); acc3 = fmaf(x3.w, w4.w, acc3);
    }
    float v0 = fmaxf(acc0, 0.0f), v1 = fmaxf(acc1, 0.0f), v2 = fmaxf(acc2, 0.0f), v3 = fmaxf(acc3, 0.0f);
    Uout[(size_t)(rbase + 0) * EMBED + c] = v0;
    Uout[(size_t)(rbase + 1) * EMBED + c] = v1;
    Uout[(size_t)(rbase + 2) * EMBED + c] = v2;
    Uout[(size_t)(rbase + 3) * EMBED + c] = v3;
    Uout16[(size_t)(rbase + 0) * EMBED + c] = __float2bfloat16(v0);
    Uout16[(size_t)(rbase + 1) * EMBED + c] = __float2bfloat16(v1);
    Uout16[(size_t)(rbase + 2) * EMBED + c] = __float2bfloat16(v2);
    Uout16[(size_t)(rbase + 3) * EMBED + c] = __float2bfloat16(v3);
}

// + fused bp/bn gather epilogue
__global__ __launch_bounds__(256) void k_layer_batch(const float* __restrict__ Agg2,
                                                     const float* __restrict__ Uin,
                                                     const int* __restrict__ bu,
                                                     float* __restrict__ out0,
                                                     const float* __restrict__ W,
                                                     const float* __restrict__ b,
                                                     const float* __restrict__ V,
                                                     const int* __restrict__ bp,
                                                     const int* __restrict__ bn) {
    __shared__ __align__(16) float Wt[64 * 128];
    int t = threadIdx.x;
    for (int i = t; i < 128 * 64; i += 256) {
        int k = i >> 6, c = i & 63;
        Wt[c * 128 + ((((k >> 2) ^ (c & 7)) << 2) | (k & 3))] = W[i];
    }
    int rl = __builtin_amdgcn_readfirstlane(t >> 6);
    int c  = t & 63;
    int sbase = blockIdx.x * 16 + rl * 4;              // 512*16 = 8192 exact
    int r0 = bu[sbase + 0], r1 = bu[sbase + 1], r2 = bu[sbase + 2], r3 = bu[sbase + 3];
    __syncthreads();
    const float4* Wt4 = (const float4*)Wt;
    int  csw   = c & 7;
    int  cbase = c * 32;
    const float4* a0 = (const float4*)(Agg2 + (size_t)(sbase + 0) * EMBED);
    const float4* a1 = (const float4*)(Agg2 + (size_t)(sbase + 1) * EMBED);
    const float4* a2 = (const float4*)(Agg2 + (size_t)(sbase + 2) * EMBED);
    const float4* a3 = (const float4*)(Agg2 + (size_t)(sbase + 3) * EMBED);
    const float4* u0 = (const float4*)(Uin + (size_t)r0 * EMBED);
    const float4* u1 = (const float4*)(Uin + (size_t)r1 * EMBED);
    const float4* u2 = (const float4*)(Uin + (size_t)r2 * EMBED);
    const float4* u3 = (const float4*)(Uin + (size_t)r3 * EMBED);
    float bias = b[c];
    float acc0 = bias, acc1 = bias, acc2 = bias, acc3 = bias;
#pragma unroll 4
    for (int k4 = 0; k4 < 16; ++k4) {
        float4 w4 = Wt4[cbase + (k4 ^ csw)];
        float4 x0 = a0[k4], x1 = a1[k4], x2 = a2[k4], x3 = a3[k4];
        acc0 = fmaf(x0.x, w4.x, acc0); acc0 = fmaf(x0.y, w4.y, acc0); acc0 = fmaf(x0.z, w4.z, acc0); acc0 = fmaf(x0.w, w4.w, acc0);
        acc1 = fmaf(x1.x, w4.x, acc1); acc1 = fmaf(x1.y, w4.y, acc1); acc1 = fmaf(x1.z, w4.z, acc1); acc1 = fmaf(x1.w, w4.w, acc1);
        acc2 = fmaf(x2.x, w4.x, acc2); acc2 = fmaf(x2.y, w4.y, acc2); acc2 = fmaf(x2.z, w4.z, acc2); acc2 = fmaf(x2.w, w4.w, acc2);
        acc3 = fmaf(x3.x, w4.x, acc3); acc3 = fmaf(x3.y, w4.y, acc3); acc3 = fmaf(x3.z, w4.z, acc3); acc3 = fmaf(x3.w, w4.w, acc3);
    }
#pragma unroll 4
    for (int k4 = 16; k4 < 32; ++k4) {
        float4 w4 = Wt4[cbase + (k4 ^ csw)];
        float4 x0 = u0[k4 - 16], x1 = u1[k4 - 16], x2 = u2[k4 - 16], x3 = u3[k4 - 16];
        acc0 = fmaf(x0.x, w4.x, acc0); acc0 = fmaf(x0.y, w4.y, acc0); acc0 = fmaf(x0.z, w4.z, acc0); acc0 = fmaf(x0.w, w4.w, acc0);
        acc1 = fmaf(x1.x, w4.x, acc1); acc1 = fmaf(x1.y, w4.y, acc1); acc1 = fmaf(x1.z, w4.z, acc1); acc1 = fmaf(x1.w, w4.w, acc1);
        acc2 = fmaf(x2.x, w4.x, acc2); acc2 = fmaf(x2.y, w4.y, acc2); acc2 = fmaf(x2.z, w4.z, acc2); acc2 = fmaf(x2.w, w4.w, acc2);
        acc3 = fmaf(x3.x, w4.x, acc3); acc3 = fmaf(x3.y, w4.y, acc3); acc3 = fmaf(x3.z, w4.z, acc3); acc3 = fmaf(x3.w, w4.w, acc3);
    }
    out0[(size_t)(sbase + 0) * EMBED + c] = fmaxf(acc0, 0.0f);
    out0[(size_t)(sbase + 1) * EMBED + c] = fmaxf(acc1, 0.0f);
    out0[(size_t)(sbase + 2) * EMBED + c] = fmaxf(acc2, 0.0f);
    out0[(size_t)(sbase + 3) * EMBED + c] = fmaxf(acc3, 0.0f);
#pragma unroll
    for (int q = 0; q < 4; ++q) {
        int s = sbase + q;
        out0[(size_t)(BATCH + s) * EMBED + c]     = V[(size_t)bp[s] * EMBED + c];
        out0[(size_t)(2 * BATCH + s) * EMBED + c] = V[(size_t)bn[s] * EMBED + c];
    }
}

// ---------------- R handling: bitmap filter -> fixed segments -> register SpMM ----------------

// single 5M-edge pass: bitmap-gated segment fill; also fused V->bf16 convert
__global__ __launch_bounds__(256) void k_rseg(const int* __restrict__ rows,
                                              const int* __restrict__ cols,
                                              const float* __restrict__ vals,
                                              const unsigned* __restrict__ bitmap,
                                              const int* __restrict__ head,
                                              int* __restrict__ cntR,
                                              int2* __restrict__ seg, int nnz,
                                              const float* __restrict__ V,
                                              __hip_bfloat16* __restrict__ V16) {
    int e = blockIdx.x * blockDim.x + threadIdx.x;
    if (e < NUM_ITEMS * EMBED) V16[e] = __float2bfloat16(V[e]);
    if (e >= nnz) return;
    int r = rows[e];
    if (!((bitmap[(unsigned)r >> 5] >> (r & 31)) & 1u)) return;
    int s   = head[r];
    int pos = atomicAdd(&cntR[s], 1);
    if (pos < SEGCAP) seg[s * SEGCAP + pos] = make_int2(cols[e], __float_as_int(vals[e]));
}

// per-chain-head gather SpMM over its segment; write once per slot along chain
__global__ __launch_bounds__(256) void k_rspmm(const int* __restrict__ cntR,
                                               const int2* __restrict__ seg,
                                               const __hip_bfloat16* __restrict__ V16,
                                               const int* __restrict__ bu,
                                               const int* __restrict__ head,
                                               const int* __restrict__ nxt,
                                               float* __restrict__ out0) {
    int s    = blockIdx.x * (blockDim.x >> 6) + (threadIdx.x >> 6);
    int lane = threadIdx.x & 63;
    if (s >= BATCH) return;
    if (head[bu[s]] != s) return;       // only chain heads own edges
    int n = cntR[s];
    if (n > SEGCAP) n = SEGCAP;
    const int2* cv2 = seg + (size_t)s * SEGCAP;
    float acc = 0.0f;
    int j    = 0;
    int jend = n & ~7;
    for (; j < jend; j += 8) {
        int2 cv[8];
#pragma unroll
        for (int u = 0; u < 8; ++u) cv[u] = cv2[j + u];
        float x[8];
#pragma unroll
        for (int u = 0; u < 8; ++u) x[u] = __bfloat162float(V16[(size_t)cv[u].x * EMBED + lane]);
#pragma unroll
        for (int u = 0; u < 8; ++u) acc = fmaf(__int_as_float(cv[u].y), x[u], acc);
    }
    for (; j < n; ++j)
        acc = fmaf(__int_as_float(cv2[j].y), __bfloat162float(V16[(size_t)cv2[j].x * EMBED + lane]), acc);
    int slot = s;
    while (slot >= 0) {
        out0[(size_t)slot * EMBED + lane] += acc;
        slot = nxt[slot];
    }
}

// ---------------- launch ----------------

extern "C" void kernel_launch(void* const* d_in, const int* in_sizes, int n_in,
                              void* d_out, int out_size, void* d_ws, size_t ws_size,
                              hipStream_t stream) {
    const int*   batch_user = (const int*)d_in[0];
    const int*   batch_pos  = (const int*)d_in[1];
    const int*   batch_neg  = (const int*)d_in[2];
    const float* U     = (const float*)d_in[3];
    const float* V     = (const float*)d_in[4];
    const float* W0    = (const float*)d_in[5];
    const float* b0    = (const float*)d_in[6];
    const float* W1    = (const float*)d_in[7];
    const float* b1    = (const float*)d_in[8];
    const int*   S_row = (const int*)d_in[9];
    const int*   S_col = (const int*)d_in[10];
    const float* S_val = (const float*)d_in[11];
    const int*   R_row = (const int*)d_in[12];
    const int*   R_col = (const int*)d_in[13];
    const float* R_val = (const float*)d_in[14];
    float* out = (float*)d_out;

    const size_t tabElems = (size_t)NUM_USERS * EMBED;   // 6.4M

    // workspace layout. Aliases: tmpE <- A; seg <- B (dead after k_layer).
    // X16 region (12.8 MB) sequentially holds U16 -> A16 -> V16.
    char* wsb = (char*)d_ws;
    size_t o = 0;
    float* A       = (float*)(wsb + o); o += tabElems * 4;            // U1 fp32 (alias: tmpE)
    float* B       = (float*)(wsb + o); o += tabElems * 4;            // agg fp32 (alias: seg)
    float* Agg2    = (float*)(wsb + o); o += (size_t)BATCH * EMBED * 4;
    int*   rowptrS = (int*)(wsb + o);   o += (NUM_USERS + 1) * 4;
    int*   cnt_t   = (int*)(wsb + o);   o += (size_t)NB * NCH * 4;    // 2 MB
    int*   bsums   = (int*)(wsb + o);   o += 1024 * 4;
    int*   head    = (int*)(wsb + o);   o += NUM_USERS * 4;
    int*   nxt     = (int*)(wsb + o);   o += BATCH * 4;
    int*   cntR    = (int*)(wsb + o);   o += BATCH * 4;
    unsigned* bitmap = (unsigned*)(wsb + o); o += ((NUM_USERS + 31) / 32) * 4;
    o = (o + 7) & ~(size_t)7;
    int2*  colvalS = (int2*)(wsb + o);  o += (size_t)S_NNZ * 8;
    __hip_bfloat16* X16 = (__hip_bfloat16*)(wsb + o); o += tabElems * 2;

    int2* tmpE = (int2*)A;
    int2* seg  = (int2*)B;   // alias: B dead after k_layer; 8192*160*8B = 10.5MB < 25.6MB

    const int pair_blocks  = (NUM_USERS / 2) / 4;        // 12500: 2 rows/wave, 4 waves/block
    const int layer_blocks = (NUM_USERS + 15) / 16;

    // ---- CSR of S: single cooperative build kernel (init+hist / scan / chain / scatter / p2) ----
    {
        void* args[] = { (void*)&S_row, (void*)&S_col, (void*)&S_val, (void*)&cnt_t,
                         (void*)&head, (void*)&bitmap, (void*)&cntR,
                         (void*)&batch_user, (void*)&nxt, (void*)&tmpE,
                         (void*)&U, (void*)&X16, (void*)&rowptrS, (void*)&colvalS, (void*)&bsums };
        hipLaunchCooperativeKernel((const void*)k_build, dim3(NCH), dim3(256), args, 0, stream);
    }

    // ---- layer 0 (full): SpMM1 2-rows/wave (U16 table), layer v2 (emits A + A16) ----
    k_spmm16p<<<pair_blocks, 256, 0, stream>>>(rowptrS, colvalS, X16, B, NUM_USERS / 2);
    k_layer<<<layer_blocks, 256, 0, stream>>>(B, U, A, X16, W0, b0);   // X16 now = A16; B dead

    // ---- layer 1 (batch): SpMM2 (A16 table), layer v2 + fused bp/bn gathers ----
    k_spmm_batch16<<<(BATCH * 64 + 255) / 256, 256, 0, stream>>>(rowptrS, colvalS, X16, batch_user, Agg2, BATCH);
    k_layer_batch<<<(BATCH + 15) / 16, 256, 0, stream>>>(Agg2, A, batch_user, out, W1, b1,
                                                         V, batch_pos, batch_neg);  // A dead

    // ---- out0 += (R @ V)[batch rows]: bitmap filter -> segments -> SpMM (cvtV fused) ----
    k_rseg<<<(R_NNZ + 255) / 256, 256, 0, stream>>>(R_row, R_col, R_val, bitmap, head, cntR, seg, R_NNZ,
                                                    V, X16);  // X16 now = V16
    k_rspmm<<<(BATCH * 64 + 255) / 256, 256, 0, stream>>>(cntR, seg, X16, batch_user, head, nxt, out);
}